// Round 5
// baseline (75.718 us; speedup 1.0000x reference)
//
#include <hip/hip_runtime.h>

#define KK 256
#define NCLS 18
#define MASK_BYTES_PER_BATCH (KK * KK)   // 65536

typedef unsigned long long ull;

// ---------------------------------------------------------------------------
// Phase 1: fully parallel per-pair flag precompute + all pass-through outputs.
// Emits codes PRE-TRANSPOSED per lane: u32 word per (row, lane) with nibble
// planes: bit (4*b + q) = bit b of code(i, j=4*lane+q).
//   b0=A, b1=B, b2=C, b3=cond(0,0), b4=cond(1,0), b5=cond(0,1), b6=cond(1,1)
// summary byte (i): bit2=tA0=(p_i<n_i), bit3=tA1=!(n_i<p_i)  (bits 0,1 unused)
// ---------------------------------------------------------------------------
__global__ __launch_bounds__(256)
void flags_kernel(const float* __restrict__ pc, const float* __restrict__ ps,
                  const float* __restrict__ ph, const float* __restrict__ sem,
                  const float* __restrict__ av,
                  unsigned char* __restrict__ ws_mask,
                  unsigned char* __restrict__ ws_sum,
                  float* __restrict__ out)
{
#pragma clang fp contract(off)
    const int blk = blockIdx.x;
    const int b   = blk >> 4;
    const int g   = blk & 15;
    const int tid = threadIdx.x;

    __shared__ float sdpn[KK][9];
    __shared__ float sc[KK][3];

    const float* pcb  = pc  + (size_t)b * 3 * KK;
    const float* psb  = ps  + (size_t)b * 3 * KK;
    const float* phb  = ph  + (size_t)b * 2 * KK;
    const float* semb = sem + (size_t)b * (2 + NCLS) * KK;
    const float* avb  = av  + (size_t)b * KK * 3;
    float* outb       = out + (size_t)b * KK * 28;

    {   // stage proposal `tid`'s derived data (identical float exprs to ref)
        const int k = tid;
        const float c0 = avb[k*3+0] + pcb[0*KK + k];
        const float c1 = avb[k*3+1] + pcb[1*KK + k];
        const float c2 = avb[k*3+2] + pcb[2*KK + k];
        const float s0 = psb[0*KK + k], s1 = psb[1*KK + k], s2 = psb[2*KK + k];
        const float h1 = phb[1*KK + k];
        const float v0 = s0 * h1, v1 = s1, v2 = s2 * h1;
        sdpn[k][0] = (v0 + c0) - fabsf(s0);
        sdpn[k][1] = (v0 + c0);
        sdpn[k][2] = (v1 + c1) - fabsf(s1);
        sdpn[k][3] = (v1 + c1);
        sdpn[k][4] = (v2 + c2) - fabsf(s2);
        sdpn[k][5] = (v2 + c2);
        sdpn[k][6] = semb[0*KK + k];
        sdpn[k][7] = semb[1*KK + k];
        sc[k][0] = c0; sc[k][1] = c1; sc[k][2] = c2;
    }
    __syncthreads();

    const int rl = tid >> 4;          // local row 0..15
    const int i  = g * 16 + rl;       // global row
    const int j0 = (tid & 15) * 16;   // 16 j's per thread (lanes j0/4 .. +3)

    const float piv = sdpn[i][6], niv = sdpn[i][7];
    const float di0 = sdpn[i][0], di1 = sdpn[i][1], di2 = sdpn[i][2];
    const float di3 = sdpn[i][3], di4 = sdpn[i][4], di5 = sdpn[i][5];
    const float ci0 = sc[i][0], ci1 = sc[i][1], ci2 = sc[i][2];

    unsigned W[4] = {0u, 0u, 0u, 0u};
#pragma unroll
    for (int t = 0; t < 16; ++t) {
        const int j = j0 + t;
        unsigned code = 0;
        if (j > i) {
            const float dx = ci0 - sc[j][0];
            const float dy = ci1 - sc[j][1];
            const float dz = ci2 - sc[j][2];
            const float dist2 = dx*dx + dy*dy + dz*dz;
            if (dist2 < 9.0f) {
                const float e0 = sdpn[j][0], e1 = sdpn[j][1], e2 = sdpn[j][2];
                const float e3 = sdpn[j][3], e4 = sdpn[j][4], e5 = sdpn[j][5];
                const bool case0 = (e0 < di0) & (e1 > di1) & (e2 < di2)
                                 & (e3 > di3) & (e4 < di4) & (e5 > di5);
                const bool case1 = (e0 > di0) & (e1 < di1) & (e2 > di2)
                                 & (e3 < di3) & (e4 > di4) & (e5 < di5);
                if (case0) {
                    code = 1u;
                } else if (case1) {
                    code = 2u;
                } else {
                    const bool ovx = ((e1 > di0) & (e1 < di1)) | ((di1 > e0) & (di1 < e1));
                    const bool ovy = ((e3 > di2) & (e3 < di3)) | ((di3 > e2) & (di3 < e3));
                    const bool ovz = ((e5 > di4) & (e5 < di5)) | ((di5 > e4) & (di5 < e5));
                    if (ovx & ovy & ovz) {
                        const float pj = sdpn[j][6], nj = sdpn[j][7];
                        const unsigned c00 = (niv < nj) ? 1u : 0u;
                        const unsigned c10 = (piv < nj) ? 1u : 0u;
                        const unsigned c01 = (niv < pj) ? 1u : 0u;
                        const unsigned c11 = (piv < pj) ? 1u : 0u;
                        code = 4u | (c00<<3) | (c10<<4) | (c01<<5) | (c11<<6);
                    }
                }
            }
        }
        // spread bit b of code to bit 4b, then shift by q = t&3
        const unsigned s = (code & 1u)        | ((code & 2u) << 3)
                         | ((code & 4u) << 6) | ((code & 8u) << 9)
                         | ((code & 16u) << 12) | ((code & 32u) << 15)
                         | ((code & 64u) << 18);
        W[t >> 2] |= s << (t & 3);
    }

    uint4 w4;
    w4.x = W[0]; w4.y = W[1]; w4.z = W[2]; w4.w = W[3];
    *(uint4*)(ws_mask + (size_t)b * MASK_BYTES_PER_BATCH + i * KK + j0) = w4;

    // pass-through outputs for this block's k-slice [g*16, g*16+16)
    for (int s = tid; s < 16 * 28; s += 256) {
        const int kk = g * 16 + (s / 28);
        const int c  = s % 28;
        if (c == 8 || c == 9) continue;      // scores written by phase 2
        float val;
        if (c < 3)       val = sc[kk][c];
        else if (c < 6)  val = psb[(c - 3) * KK + kk];
        else if (c < 8)  val = phb[(c - 6) * KK + kk];
        else             val = semb[(c - 8) * KK + kk];
        outb[(size_t)kk * 28 + c] = val;
    }

    if (tid < 16) {
        const int i2 = g * 16 + tid;
        const unsigned tab = ((sdpn[i2][6] < sdpn[i2][7]) ? 4u : 0u)
                           | ((sdpn[i2][7] < sdpn[i2][6]) ? 0u : 8u);
        ws_sum[b * KK + i2] = (unsigned char)tab;
    }
}

// ---------------------------------------------------------------------------
// Phase 2: one wave per batch. Affine (GF(2)) row body:
//  - per-lane 4-bit kill/beta vectors (flat bit ops, no compose trees)
//  - 2 ballots -> uniform SALU doubling scan gives the whole entry-state word
//  - per-lane tail: one 64-bit shift + a handful of selects
// ---------------------------------------------------------------------------
__global__ __launch_bounds__(64)
void suppress5_kernel(const float* __restrict__ sem,
                      const unsigned char* __restrict__ ws_mask,
                      const unsigned char* __restrict__ ws_sum,
                      float* __restrict__ out)
{
    const int b    = blockIdx.x;
    const int lane = threadIdx.x;

    __shared__ unsigned s_mask[KK * 64];   // 64 KB: linear copy of batch codes

    const float* semb = sem + (size_t)b * (2 + NCLS) * KK;
    float* outb       = out + (size_t)b * KK * 28;

    // stage codes: global -> LDS, 8 x 16B in flight per sweep group
    const uint4* gm = (const uint4*)(ws_mask + (size_t)b * MASK_BYTES_PER_BATCH);
    uint4* sm4 = (uint4*)s_mask;
    for (int so = 0; so < 64; so += 8) {
        uint4 v[8];
#pragma unroll
        for (int t = 0; t < 8; ++t) v[t] = gm[(so + t) * 64 + lane];
#pragma unroll
        for (int t = 0; t < 8; ++t) sm4[(so + t) * 64 + lane] = v[t];
    }

    float pj[4], nj[4];
    unsigned Ljm = 0, Gjm = 0, bmask = 0;
#pragma unroll
    for (int q = 0; q < 4; ++q) {
        const int k = lane * 4 + q;
        const float p = semb[0*KK + k];
        const float n = semb[1*KK + k];
        pj[q] = p; nj[q] = n;
        if (p < n) Ljm |= 1u << q;
        if (n < p) Gjm |= 1u << q;
    }
    const unsigned nGjm = (~Gjm) & 0xFu;

    // summary bytes -> row-uniform tA bitmaps via ballots
    const unsigned char* sbp = ws_sum + b * KK;
    const unsigned sb0 = sbp[lane], sb1 = sbp[64 + lane],
                   sb2 = sbp[128 + lane], sb3 = sbp[192 + lane];
    const ull a0_0 = __ballot(sb0 & 4u), a1_0 = __ballot(sb0 & 8u);
    const ull a0_1 = __ballot(sb1 & 4u), a1_1 = __ballot(sb1 & 8u);
    const ull a0_2 = __ballot(sb2 & 4u), a1_2 = __ballot(sb2 & 8u);
    const ull a0_3 = __ballot(sb3 & 4u), a1_3 = __ballot(sb3 & 8u);

    __syncthreads();   // staging complete

#define ROWBODY(i_, tA0_, tA1_) { \
        const unsigned m = mcur; \
        const int slot = (i_) & 3, owner = (i_) >> 2; \
        const unsigned kmask4 = ((tA0_) ^ (tA1_)) ? 0u : 0xFu; \
        const unsigned vmask4 = (tA0_) ? 0xFu : 0u; \
        /* b_start ballot: off the main chain */ \
        const ull bsb = __ballot(((bmask >> slot) & 1u) != 0u); \
        /* nibble-plane extracts (bfe each) */ \
        const unsigned isA4 = m & 0xFu; \
        const unsigned isB4 = (m >> 4) & 0xFu; \
        const unsigned isC4 = (m >> 8) & 0xFu; \
        const unsigned e3n = (m >> 12) & 0xFu; \
        const unsigned e4n = (m >> 16) & 0xFu; \
        const unsigned e5n = (m >> 20) & 0xFu; \
        const unsigned e6n = (m >> 24) & 0xFu; \
        const unsigned bm = bmask; \
        /* cond(x=0/1) given current b_j */ \
        const unsigned c0v = (e5n & bm) | (e3n & ~bm); \
        const unsigned c1v = (e6n & bm) | (e4n & ~bm); \
        /* affine per-step: kill = ~a, beta */ \
        const unsigned KV = (isA4 & kmask4) | (isC4 & (c0v ^ c1v)); \
        const unsigned BV = (isA4 & vmask4) | (isC4 & c0v); \
        const unsigned A4 = KV ^ 0xFu; \
        /* local exclusive prefix (entry 0): av0_q = state before step q */ \
        const unsigned As = A4 << 1; \
        const unsigned Bs = BV << 1; \
        const unsigned B2 = Bs ^ (As & (Bs << 1)); \
        const unsigned A2 = As & (As << 1); \
        const unsigned av0 = B2 ^ (A2 & (B2 << 2)); \
        /* exclusive prefix-AND of a (pa_q = a0..a_{q-1}) */ \
        const unsigned y  = As | 1u; \
        const unsigned z1 = y & ((y << 1) | 1u); \
        const unsigned pa = z1 & ((z1 << 2) | 3u); \
        const unsigned aTv = pa & A4;           /* bit3 = lane-total a */ \
        const unsigned FS  = (A4 & av0) ^ BV;   /* bit3 = lane beta / const value */ \
        const ull cm = __ballot((aTv & 8u) == 0u); \
        const ull Fm = __ballot((FS & 8u) != 0u); \
        /* uniform SALU affine doubling scan -> entry-state word EW */ \
        ull A = (~cm << 1) | 1ull; \
        ull B = Fm << 1; \
        B ^= A & (B << 1);  A &= (A << 1)  | 1ull; \
        B ^= A & (B << 2);  A &= (A << 2)  | 3ull; \
        B ^= A & (B << 4);  A &= (A << 4)  | 15ull; \
        B ^= A & (B << 8);  A &= (A << 8)  | 255ull; \
        B ^= A & (B << 16); A &= (A << 16) | 0xFFFFull; \
        B ^= A & (B << 32); A &= (A << 32) | 0xFFFFFFFFull; \
        const unsigned b_start = (unsigned)((bsb >> owner) & 1ull); \
        const ull EW = B ^ (b_start ? A : 0ull); \
        const unsigned bfin = (unsigned)(((((~cm) & EW) ^ Fm) >> 63) & 1ull); \
        /* per-lane tail: C flips from per-step entry states */ \
        const unsigned nc0 = isC4 & (c0v ^ 0xFu); \
        const unsigned nc1 = isC4 & (c1v ^ 0xFu); \
        const unsigned El = (unsigned)((EW >> lane) & 1ull); \
        const unsigned Emask = El ? 0xFu : 0u; \
        const unsigned sv = av0 ^ (pa & Emask); \
        const unsigned flips = (nc1 & sv) | (nc0 & ~sv); \
        /* B side-effects */ \
        const unsigned nbv = (nGjm & bm) | (Ljm & ~bm); \
        unsigned nbm = ((nbv & isB4) | (bm & ~isB4)) ^ flips; \
        /* owner fixup */ \
        const unsigned fixed = (nbm & ~(1u << slot)) | (bfin << slot); \
        bmask = (lane == owner) ? fixed : nbm; }

#define RUNCHUNK(W_, A0w, A1w, NROWS) \
    for (int bb = 0; bb < (NROWS); ++bb) { \
        const int i_ = ((W_) << 6) + bb; \
        const unsigned mnext = s_mask[(i_ + 1) * 64 + lane]; \
        const unsigned t0_ = (unsigned)(((A0w) >> bb) & 1ull); \
        const unsigned t1_ = (unsigned)(((A1w) >> bb) & 1ull); \
        ROWBODY(i_, t0_, t1_) \
        mcur = mnext; \
    }

    unsigned mcur = s_mask[lane];   // row 0
    RUNCHUNK(0, a0_0, a1_0, 64)
    RUNCHUNK(1, a0_1, a1_1, 64)
    RUNCHUNK(2, a0_2, a1_2, 64)
    RUNCHUNK(3, a0_3, a1_3, 63)

#undef RUNCHUNK
#undef ROWBODY

#pragma unroll
    for (int q = 0; q < 4; ++q) {
        const int k = lane * 4 + q;
        const unsigned bq = (bmask >> q) & 1u;
        outb[k*28 + 8] = bq ? nj[q] : pj[q];
        outb[k*28 + 9] = bq ? pj[q] : nj[q];
    }
}

// ---------------------------------------------------------------------------
// Fallback (round-1 verified kernel) in case ws_size is too small.
// ---------------------------------------------------------------------------
__device__ __forceinline__ unsigned compose2(unsigned a, unsigned b) {
    unsigned r0 = (b >> (a & 1u)) & 1u;
    unsigned r1 = (b >> ((a >> 1) & 1u)) & 1u;
    return r0 | (r1 << 1u);
}

__global__ __launch_bounds__(64)
void proposal_suppress_kernel(const float* __restrict__ pc, const float* __restrict__ ps,
                              const float* __restrict__ ph, const float* __restrict__ sem,
                              const float* __restrict__ av, float* __restrict__ out)
{
#pragma clang fp contract(off)
    const int b    = blockIdx.x;
    const int lane = threadIdx.x;

    __shared__ float s_p[KK], s_n[KK], s_d[KK][6], s_c[KK][3];

    const float* pcb  = pc  + (size_t)b * 3 * KK;
    const float* psb  = ps  + (size_t)b * 3 * KK;
    const float* phb  = ph  + (size_t)b * 2 * KK;
    const float* semb = sem + (size_t)b * (2 + NCLS) * KK;
    const float* avb  = av  + (size_t)b * KK * 3;
    float* outb       = out + (size_t)b * KK * 28;

    float pj[4], nj[4], dj[4][6], cj[4][3];
    unsigned Ljm = 0, Gjm = 0, bmask = 0;

#pragma unroll
    for (int q = 0; q < 4; ++q) {
        const int k = lane * 4 + q;
        const float c0 = avb[k*3+0] + pcb[0*KK + k];
        const float c1 = avb[k*3+1] + pcb[1*KK + k];
        const float c2 = avb[k*3+2] + pcb[2*KK + k];
        const float s0 = psb[0*KK + k], s1 = psb[1*KK + k], s2 = psb[2*KK + k];
        const float h0 = phb[0*KK + k], h1 = phb[1*KK + k];
        const float v0 = s0 * h1, v1 = s1, v2 = s2 * h1;
        float d[6];
        d[0] = (v0 + c0) - fabsf(s0); d[1] = (v0 + c0);
        d[2] = (v1 + c1) - fabsf(s1); d[3] = (v1 + c1);
        d[4] = (v2 + c2) - fabsf(s2); d[5] = (v2 + c2);
        const float p = semb[0*KK + k];
        const float n = semb[1*KK + k];
        cj[q][0] = c0; cj[q][1] = c1; cj[q][2] = c2;
#pragma unroll
        for (int m = 0; m < 6; ++m) dj[q][m] = d[m];
        pj[q] = p; nj[q] = n;
        if (p < n) Ljm |= 1u << q;
        if (n < p) Gjm |= 1u << q;
        s_p[k] = p; s_n[k] = n;
#pragma unroll
        for (int m = 0; m < 6; ++m) s_d[k][m] = d[m];
        s_c[k][0] = c0; s_c[k][1] = c1; s_c[k][2] = c2;
        outb[k*28 + 0] = c0; outb[k*28 + 1] = c1; outb[k*28 + 2] = c2;
        outb[k*28 + 3] = s0; outb[k*28 + 4] = s1; outb[k*28 + 5] = s2;
        outb[k*28 + 6] = h0; outb[k*28 + 7] = h1;
#pragma unroll
        for (int cc = 0; cc < NCLS; ++cc)
            outb[k*28 + 10 + cc] = semb[(2 + cc)*KK + k];
    }
    __syncthreads();

    const unsigned ID = 2u;
    for (int i = 0; i < KK - 1; ++i) {
        const float piv = s_p[i], niv = s_n[i];
        const float di0 = s_d[i][0], di1 = s_d[i][1], di2 = s_d[i][2];
        const float di3 = s_d[i][3], di4 = s_d[i][4], di5 = s_d[i][5];
        const float ci0 = s_c[i][0], ci1 = s_c[i][1], ci2 = s_c[i][2];
        const unsigned tA = (piv < niv ? 1u : 0u) | ((niv < piv ? 0u : 1u) << 1);
        const int owner = i >> 2, slot = i & 3;

        unsigned tq[4];
        unsigned Cq = 0, cc0m = 0, cc1m = 0;
        unsigned tl = ID;
#pragma unroll
        for (int q = 0; q < 4; ++q) {
            const int j = lane * 4 + q;
            unsigned t = ID;
            if (j > i) {
                const float dx = ci0 - cj[q][0];
                const float dy = ci1 - cj[q][1];
                const float dz = ci2 - cj[q][2];
                const float dist2 = dx*dx + dy*dy + dz*dz;
                if (dist2 < 9.0f) {
                    const bool case0 = (dj[q][0] < di0) & (dj[q][1] > di1)
                                     & (dj[q][2] < di2) & (dj[q][3] > di3)
                                     & (dj[q][4] < di4) & (dj[q][5] > di5);
                    const bool case1 = (dj[q][0] > di0) & (dj[q][1] < di1)
                                     & (dj[q][2] > di2) & (dj[q][3] < di3)
                                     & (dj[q][4] > di4) & (dj[q][5] < di5);
                    if (case0) {
                        t = tA;
                    } else if (case1) {
                        const unsigned bj = (bmask >> q) & 1u;
                        const unsigned nb = bj ? (((Gjm >> q) & 1u) ? 0u : 1u)
                                               : (((Ljm >> q) & 1u) ? 1u : 0u);
                        bmask = (bmask & ~(1u << q)) | (nb << q);
                    } else {
                        const bool ovx = ((dj[q][1] > di0) & (dj[q][1] < di1))
                                       | ((di1 > dj[q][0]) & (di1 < dj[q][1]));
                        const bool ovy = ((dj[q][3] > di2) & (dj[q][3] < di3))
                                       | ((di3 > dj[q][2]) & (di3 < dj[q][3]));
                        const bool ovz = ((dj[q][5] > di4) & (dj[q][5] < di5))
                                       | ((di5 > dj[q][4]) & (di5 < dj[q][5]));
                        if (ovx & ovy & ovz) {
                            const unsigned bj = (bmask >> q) & 1u;
                            const float sj = bj ? pj[q] : nj[q];
                            const unsigned c0b = (niv < sj) ? 1u : 0u;
                            const unsigned c1b = (piv < sj) ? 1u : 0u;
                            t = c0b | ((c1b ^ 1u) << 1u);
                            Cq |= 1u << q; cc0m |= c0b << q; cc1m |= c1b << q;
                        }
                    }
                }
            }
            tq[q] = t;
            tl = compose2(tl, t);
        }

        const ull any = __ballot((tl != ID) || (Cq != 0));
        if (any == 0ull) continue;

        const unsigned b_start = (((unsigned)__shfl((int)bmask, owner, 64)) >> slot) & 1u;

        unsigned incl = tl;
#pragma unroll
        for (int off = 1; off < 64; off <<= 1) {
            const unsigned other = (unsigned)__shfl_up((int)incl, (unsigned)off, 64);
            if (lane >= off) incl = compose2(other, incl);
        }
        const unsigned total = (unsigned)__shfl((int)incl, 63, 64);
        const unsigned upv   = (unsigned)__shfl_up((int)incl, 1u, 64);
        const unsigned excl  = (lane == 0) ? ID : upv;

        unsigned cur = (excl >> b_start) & 1u;
#pragma unroll
        for (int q = 0; q < 4; ++q) {
            if ((Cq >> q) & 1u) {
                const unsigned cond = cur ? ((cc1m >> q) & 1u) : ((cc0m >> q) & 1u);
                if (!cond) bmask ^= (1u << q);
            }
            cur = (tq[q] >> cur) & 1u;
        }
        if (lane == owner) {
            const unsigned nbi = (total >> b_start) & 1u;
            bmask = (bmask & ~(1u << slot)) | (nbi << slot);
        }
    }

#pragma unroll
    for (int q = 0; q < 4; ++q) {
        const int k = lane * 4 + q;
        const unsigned bq = (bmask >> q) & 1u;
        outb[k*28 + 8] = bq ? nj[q] : pj[q];
        outb[k*28 + 9] = bq ? pj[q] : nj[q];
    }
}

extern "C" void kernel_launch(void* const* d_in, const int* in_sizes, int n_in,
                              void* d_out, int out_size, void* d_ws, size_t ws_size,
                              hipStream_t stream) {
    const float* pc  = (const float*)d_in[0];
    const float* ps  = (const float*)d_in[1];
    const float* ph  = (const float*)d_in[2];
    const float* sem = (const float*)d_in[3];
    const float* av  = (const float*)d_in[4];
    float* out = (float*)d_out;
    const int B = in_sizes[0] / (3 * KK);

    const size_t need = (size_t)B * MASK_BYTES_PER_BATCH + (size_t)B * KK;
    if (ws_size >= need) {
        unsigned char* wm   = (unsigned char*)d_ws;
        unsigned char* wsum = wm + (size_t)B * MASK_BYTES_PER_BATCH;
        flags_kernel<<<dim3(B * 16), dim3(256), 0, stream>>>(pc, ps, ph, sem, av, wm, wsum, out);
        suppress5_kernel<<<dim3(B), dim3(64), 0, stream>>>(sem, wm, wsum, out);
    } else {
        proposal_suppress_kernel<<<dim3(B), dim3(64), 0, stream>>>(pc, ps, ph, sem, av, out);
    }
}